// Round 13
// baseline (58.550 us; speedup 1.0000x reference)
//
#include <hip/hip_runtime.h>

// corr via MFMA band extraction, 2-row epochs, LDS-coalesced stores.
// out[b,di*9+(dj+4),h,w] = sum_c x[b,c,h,w] * y[b,c,refl(h+di-4),refl(w+dj)]
// A = Y_bf16[w'-tile, c], B = X_bf16[c, w-tile]; D[w',w] diagonals = dj.
// R13 = R12 with 2 output rows per barrier pair (epoch): rows h,h+1 share the
// 10-slot y ring exactly; pstage holds didx 0..79 for both rows (didx=80 goes
// direct); readback vectorized to float2. 1 barrier/row instead of 2.
// LDS = 30720 (ring) + 2*5120 (pstage) = 40960 exactly -> 4 blocks/CU.

#define HH   256
#define WW   256
#define CCH  64
#define KRAD 4
#define ND   81

#define WT   16                 // output w per block
#define HT   16                 // output h per block
#define NEP  8                  // epochs of 2 rows
#define WY   24                 // staged y width = WT + 2*KRAD
#define RSTRIDE 128             // bytes per (row,w'): 64c*2B, XOR-swizzled chunks
#define YRING 10
#define YSLOT (WY * RSTRIDE)    // 3072 B
#define PRS   64                // pstage row stride = exactly 16 floats
#define PROWS 80                // didx 0..79 staged; didx 80 stored direct
#define PSLOT (PROWS * PRS)     // 5120 B

typedef __attribute__((ext_vector_type(8))) short bf16x8;
typedef __attribute__((ext_vector_type(4))) float f32x4;
typedef __attribute__((ext_vector_type(2))) float f32x2;

__device__ __forceinline__ int reflect(int v, int n) {
    v = v < 0 ? -v : v;
    return v >= n ? 2 * n - 2 - v : v;
}
__device__ __forceinline__ unsigned f2bf_pk(float a, float b) {
    union { float f; unsigned u; } xa, xb;
    xa.f = a; xb.f = b;
    unsigned ra = (xa.u + 0x7fffu + ((xa.u >> 16) & 1u)) >> 16;
    unsigned rb = (xb.u + 0x7fffu + ((xb.u >> 16) & 1u)) >> 16;
    return ra | (rb << 16);
}
__device__ __forceinline__ int mod10(int s) {   // s in [0, 30)
    if (s >= 20) s -= 20; else if (s >= 10) s -= 10;
    return s;
}

__global__ __launch_bounds__(256, 4) void corr_mfma_kernel(
    const float* __restrict__ x, const float* __restrict__ y,
    float* __restrict__ out)
{
    __shared__ char lds[YRING * YSLOT + 2 * PSLOT];   // 40960 B exactly
    char* ylds   = lds;
    char* pstage = lds + YRING * YSLOT;

    // XCD-chunked bijective swizzle: 1024 blocks = 8 XCDs * 128
    const int d  = blockIdx.x;
    const int v  = (d & 7) * 128 + (d >> 3);
    const int b  = v >> 8;
    const int by = (v >> 4) & 15;
    const int bx = v & 15;
    const int w0 = bx * WT;
    const int h0 = by * HT;

    const int t    = threadIdx.x;
    const int wid  = t >> 6;
    const int lane = t & 63;
    const int lq   = lane >> 4;      // 0..3
    const int ln   = lane & 15;      // 0..15

    const size_t plane = (size_t)HH * WW;
    const float* yb = y + (size_t)b * CCH * plane;
    const float* xb = x + (size_t)b * CCH * plane;
    float* outb = out + (size_t)b * ND * plane;

    // staging lane mapping for Y rows
    const int yp  = t & 31;          // w' position, active < WY
    const int ycg = t >> 5;          // c group: c = 8*ycg + j

    auto loadY = [&](int L, float* v8) {         // L: local row (global h = h0-4+L)
        int gh = reflect(h0 - KRAD + L, HH);
        int pc = yp < WY ? yp : WY - 1;
        int gw = reflect(w0 - KRAD + pc, WW);
        const float* src = yb + (size_t)(ycg * 8) * plane + (size_t)gh * WW + gw;
#pragma unroll
        for (int j = 0; j < 8; ++j) v8[j] = src[(size_t)j * plane];
    };
    auto writeY = [&](int L, const float* v8) {
        if (yp < WY) {
            char* dst = ylds + mod10(L) * YSLOT + yp * RSTRIDE
                      + (((unsigned)(ycg * 16)) ^ ((unsigned)(yp & 7) << 4));
            union { unsigned u[4]; uint4 q; } pk;
#pragma unroll
            for (int m = 0; m < 4; ++m)
                pk.u[m] = f2bf_pk(v8[2 * m], v8[2 * m + 1]);
            *(uint4*)dst = pk.q;
        }
    };
    // X direct-to-register: lane (lq,ln) holds B[c = lq*8+j (+32), w0+ln]
    auto loadX = [&](int hrow, float* v16) {
        int gh = reflect(hrow, HH);
        const float* src = xb + (size_t)(lq * 8) * plane + (size_t)gh * WW + (w0 + ln);
#pragma unroll
        for (int j = 0; j < 8; ++j) v16[j] = src[(size_t)j * plane];
        const float* src2 = src + (size_t)32 * plane;
#pragma unroll
        for (int j = 0; j < 8; ++j) v16[8 + j] = src2[(size_t)j * plane];
    };
    auto xconv = [&](const float* v16, bf16x8& f0, bf16x8& f1) {
        union { unsigned u[4]; bf16x8 v; } c0, c1;
#pragma unroll
        for (int m = 0; m < 4; ++m) {
            c0.u[m] = f2bf_pk(v16[2 * m], v16[2 * m + 1]);
            c1.u[m] = f2bf_pk(v16[8 + 2 * m], v16[9 + 2 * m]);
        }
        f0 = c0.v; f1 = c1.v;
    };

    float yv[8], yv2[8], yva[8], yvb[8], xva[16], xvb[16];
    bf16x8 bfA0, bfA1, bfB0, bfB1;

    const int mbase = lq * 4;
    const unsigned sw = ((unsigned)(ln & 7)) << 4;

    // ---- prologue: Y rows L=0..9 -> ring (2-deep pipelined); X rows h0,h0+1 ----
    loadY(0, yv);
#pragma unroll 1
    for (int j = 0; j < 10; ++j) {
        if (j < 9) loadY(j + 1, yv2);
        writeY(j, yv);
#pragma unroll
        for (int m = 0; m < 8; ++m) yv[m] = yv2[m];
    }
    loadX(h0, xva);
    loadX(h0 + 1, xvb);
    __syncthreads();

    // ---- main loop: 8 epochs x 2 rows ----
#pragma unroll 1
    for (int ep = 0; ep < NEP; ++ep) {
        const int h = h0 + 2 * ep;
        const bool pf = (ep < NEP - 1);

        // issue next-epoch Y loads first (longest cover), then convert X,
        // then issue next-epoch X loads (consumed next epoch top).
        if (pf) { loadY(2 * ep + 10, yva); loadY(2 * ep + 11, yvb); }
        xconv(xva, bfA0, bfA1);
        xconv(xvb, bfB0, bfB1);
        if (pf) { loadX(h + 2, xva); loadX(h + 3, xvb); }

        // compute both rows: 18 (di,wt) units split 5/5/4/4 across waves
        for (int u = wid; u < 18; u += 4) {
            const int di = u >> 1;
            const int wt = u & 1;
            const int s0 = mod10(2 * ep + di);
            const int s1 = mod10(2 * ep + 1 + di);
            const char* a0 = ylds + s0 * YSLOT + (wt * 16 + ln) * RSTRIDE;
            const char* a1 = ylds + s1 * YSLOT + (wt * 16 + ln) * RSTRIDE;
            bf16x8 af00 = *(const bf16x8*)(a0 + (((unsigned)(lq * 16)) ^ sw));
            bf16x8 af01 = *(const bf16x8*)(a0 + (((unsigned)(64 + lq * 16)) ^ sw));
            bf16x8 af10 = *(const bf16x8*)(a1 + (((unsigned)(lq * 16)) ^ sw));
            bf16x8 af11 = *(const bf16x8*)(a1 + (((unsigned)(64 + lq * 16)) ^ sw));
            f32x4 d0 = {0.f, 0.f, 0.f, 0.f};
            f32x4 d1 = {0.f, 0.f, 0.f, 0.f};
            d0 = __builtin_amdgcn_mfma_f32_16x16x32_bf16(af00, bfA0, d0, 0, 0, 0);
            d0 = __builtin_amdgcn_mfma_f32_16x16x32_bf16(af01, bfA1, d0, 0, 0, 0);
            d1 = __builtin_amdgcn_mfma_f32_16x16x32_bf16(af10, bfB0, d1, 0, 0, 0);
            d1 = __builtin_amdgcn_mfma_f32_16x16x32_bf16(af11, bfB1, d1, 0, 0, 0);
#pragma unroll
            for (int r = 0; r < 4; ++r) {
                const int vrr = mbase + r - ln + (wt ? 16 : 0);   // dj+4
                if ((unsigned)vrr <= 8u) {
                    const int didx = di * 9 + vrr;
                    if (didx < PROWS) {
                        *(float*)(pstage + didx * PRS + ln * 4) = d0[r];
                        *(float*)(pstage + PSLOT + didx * PRS + ln * 4) = d1[r];
                    } else {   // didx == 80: direct store (8 lanes of unit u=17)
                        outb[(size_t)80 * plane + (size_t)h * WW + (w0 + ln)] = d0[r];
                        outb[(size_t)80 * plane + (size_t)(h + 1) * WW + (w0 + ln)] = d1[r];
                    }
                }
            }
        }

        // barrier 1: pstage writes + all ring reads complete
        __builtin_amdgcn_sched_barrier(0);
        asm volatile("s_waitcnt lgkmcnt(0)" ::: "memory");
        __builtin_amdgcn_s_barrier();
        __builtin_amdgcn_sched_barrier(0);

        // phase 2: stage next 2 Y rows (slots of retired rows 2ep-4,2ep-3)
        if (pf) { writeY(2 * ep + 10, yva); writeY(2 * ep + 11, yvb); }

        // coalesced readback: 160 virtual rows (80 didx x 2 h) of 16 floats
        {
#pragma unroll
            for (int p = 0; p < 5; ++p) {
                const int idx = t + 256 * p;      // 0..1279
                const int row = idx >> 3;         // 0..159
                const int c2  = idx & 7;
                f32x2 vv = *(const f32x2*)(pstage + row * PRS + c2 * 8);
                const int didx = (row < PROWS) ? row : row - PROWS;
                const int hr   = (row < PROWS) ? h : h + 1;
                *(f32x2*)(outb + (size_t)didx * plane + (size_t)hr * WW
                          + (w0 + c2 * 2)) = vv;
            }
        }

        // barrier 2: readback + writeY complete before next epoch
        __builtin_amdgcn_sched_barrier(0);
        asm volatile("s_waitcnt lgkmcnt(0)" ::: "memory");
        __builtin_amdgcn_s_barrier();
        __builtin_amdgcn_sched_barrier(0);
    }
}

extern "C" void kernel_launch(void* const* d_in, const int* in_sizes, int n_in,
                              void* d_out, int out_size, void* d_ws, size_t ws_size,
                              hipStream_t stream) {
    const float* x = (const float*)d_in[0];
    const float* y = (const float*)d_in[1];
    float* out = (float*)d_out;

    dim3 grid(1024);   // 16 w-tiles * 16 h-tiles * 4 batch, XCD-swizzled in-kernel
    dim3 block(256);
    corr_mfma_kernel<<<grid, block, 0, stream>>>(x, y, out);
}